// Round 1
// baseline (1163.907 us; speedup 1.0000x reference)
//
#include <hip/hip_runtime.h>

// GridSamplePScan on MI355X.
// 5 log-scan passes (step=1,2,4,8,16). Each pass: per output pixel compute the
// wrapped sample grid from the current flow, bilinear-sample previous flow
// (border pad) and previous image (zeros pad), add, write.
// Images ping-pong between d_in[1] and d_out (harness restores d_in each call);
// flows ping-pong inside d_ws (2 x 16 MiB).

constexpr int Bn = 4, Ln = 32, Cn = 16, Hn = 128, Wn = 128;
constexpr int HWp = Hn * Wn;            // 16384
constexpr int FLOW_ELEMS = Bn * Ln * 2 * HWp;   // 4,194,304
constexpr int TOTAL_PIX = Bn * Ln * HWp;        // 2,097,152

template<bool WRITE_FLOW>
__global__ __launch_bounds__(256)
void pscan_pass(const float* __restrict__ flowIn,
                const float* __restrict__ imgIn,
                float* __restrict__ flowOut,
                float* __restrict__ imgOut,
                int step)
{
    const int tid = blockIdx.x * 256 + threadIdx.x;
    const int w = tid & (Wn - 1);
    const int h = (tid >> 7) & (Hn - 1);
    const int l = (tid >> 14) & (Ln - 1);
    const int b = tid >> 19;
    const int pix = h * Wn + w;
    const int fbase = ((b * Ln + l) * 2) * HWp + pix;
    const int ibase = ((b * Ln + l) * Cn) * HWp + pix;

    if (l < step) {   // prefix: plain copy (wave-uniform branch: l fixed per block)
        if (WRITE_FLOW) {
            flowOut[fbase]       = flowIn[fbase];
            flowOut[fbase + HWp] = flowIn[fbase + HWp];
        }
        #pragma unroll
        for (int c = 0; c < Cn; ++c)
            imgOut[ibase + c * HWp] = imgIn[ibase + c * HWp];
        return;
    }

    // current flow -> sample grid
    const float fcx = flowIn[fbase];
    const float fcy = flowIn[fbase + HWp];
    float gx = (w + 0.5f) * (2.0f / Wn) - 1.0f + fcx;
    float gy = (h + 0.5f) * (2.0f / Hn) - 1.0f + fcy;

    // wrap x: remainder(gx+1, 2) - 1  (numpy mod semantics, divisor > 0)
    float t = gx + 1.0f;
    float r = fmodf(t, 2.0f);
    if (r < 0.0f) r += 2.0f;
    const float gxw = r - 1.0f;

    // unnormalize (align_corners=False)
    const float x = (gxw + 1.0f) * (Wn * 0.5f) - 0.5f;
    const float y = (gy  + 1.0f) * (Hn * 0.5f) - 0.5f;
    const float x0f = floorf(x), y0f = floorf(y);
    const float wx = x - x0f,    wy = y - y0f;
    const int x0 = (int)x0f, y0 = (int)y0f;
    const int x1 = x0 + 1,   y1 = y0 + 1;

    const int xc0 = min(max(x0, 0), Wn - 1), xc1 = min(max(x1, 0), Wn - 1);
    const int yc0 = min(max(y0, 0), Hn - 1), yc1 = min(max(y1, 0), Hn - 1);
    const int o00 = yc0 * Wn + xc0, o01 = yc0 * Wn + xc1;
    const int o10 = yc1 * Wn + xc0, o11 = yc1 * Wn + xc1;

    const float w00 = (1.0f - wx) * (1.0f - wy);
    const float w01 = wx * (1.0f - wy);
    const float w10 = (1.0f - wx) * wy;
    const float w11 = wx * wy;

    // ---- flows: border padding (clamped, unmasked) ----
    if (WRITE_FLOW) {
        const int fprev = ((b * Ln + (l - step)) * 2) * HWp;
        const float* __restrict__ fp0 = flowIn + fprev;
        const float* __restrict__ fp1 = flowIn + fprev + HWp;
        const float sx = w00 * fp0[o00] + w01 * fp0[o01] + w10 * fp0[o10] + w11 * fp0[o11];
        const float sy = w00 * fp1[o00] + w01 * fp1[o01] + w10 * fp1[o10] + w11 * fp1[o11];
        flowOut[fbase]       = fcx + sx;
        flowOut[fbase + HWp] = fcy + sy;
    }

    // ---- images: zeros padding (mask folded into weights) ----
    const bool vx0 = (x0 >= 0) & (x0 < Wn);
    const bool vx1 = (x1 >= 0) & (x1 < Wn);
    const bool vy0 = (y0 >= 0) & (y0 < Hn);
    const bool vy1 = (y1 >= 0) & (y1 < Hn);
    const float m00 = (vy0 & vx0) ? w00 : 0.0f;
    const float m01 = (vy0 & vx1) ? w01 : 0.0f;
    const float m10 = (vy1 & vx0) ? w10 : 0.0f;
    const float m11 = (vy1 & vx1) ? w11 : 0.0f;

    const int iprev = ((b * Ln + (l - step)) * Cn) * HWp;
    const float* __restrict__ ip = imgIn + iprev;
    #pragma unroll
    for (int c = 0; c < Cn; ++c) {
        const int co = c * HWp;
        const float icv = imgIn[ibase + co];
        const float v = m00 * ip[co + o00] + m01 * ip[co + o01]
                      + m10 * ip[co + o10] + m11 * ip[co + o11];
        imgOut[ibase + co] = icv + v;
    }
}

extern "C" void kernel_launch(void* const* d_in, const int* in_sizes, int n_in,
                              void* d_out, int out_size, void* d_ws, size_t ws_size,
                              hipStream_t stream) {
    const float* f_in = (const float*)d_in[0];   // flows  [4,32,2,128,128]
    float* i_io       = (float*)d_in[1];         // images [4,32,16,128,128] (harness restores each call)
    float* i_out      = (float*)d_out;

    float* fA = (float*)d_ws;            // 16 MiB
    float* fB = fA + FLOW_ELEMS;         // 16 MiB

    const int nblk = TOTAL_PIX / 256;    // 8192

    // pass 1, step=1 : flows IN->fA, images IN->OUT
    pscan_pass<true ><<<nblk, 256, 0, stream>>>(f_in, i_io, fA, i_out, 1);
    // pass 2, step=2 : flows fA->fB, images OUT->IN
    pscan_pass<true ><<<nblk, 256, 0, stream>>>(fA, i_out, fB, i_io, 2);
    // pass 3, step=4 : flows fB->fA, images IN->OUT
    pscan_pass<true ><<<nblk, 256, 0, stream>>>(fB, i_io, fA, i_out, 4);
    // pass 4, step=8 : flows fA->fB, images OUT->IN
    pscan_pass<true ><<<nblk, 256, 0, stream>>>(fA, i_out, fB, i_io, 8);
    // pass 5, step=16: flows read fB (no write), images IN->OUT
    pscan_pass<false><<<nblk, 256, 0, stream>>>(fB, i_io, nullptr, i_out, 16);
}